// Round 9
// baseline (924.298 us; speedup 1.0000x reference)
//
#include <hip/hip_runtime.h>

#define DIMM 1024
#define NHEADS 16
#define DHEAD 64
#define BATCH 4
#define SEQ 2048
#define TCTX 77
#define CTXD 768
#define FFI 4096

typedef float f32x4 __attribute__((ext_vector_type(4)));
typedef __bf16 bf16x8 __attribute__((ext_vector_type(8)));

__device__ __forceinline__ float bf2f(unsigned short u){
  union { unsigned int i; float f; } c; c.i = ((unsigned int)u) << 16; return c.f;
}
__device__ __forceinline__ unsigned short f2bf(float f){
  union { float f; unsigned int i; } c; c.f = f;
  unsigned int i = c.i;
  return (unsigned short)((i + 0x7fffu + ((i >> 16) & 1u)) >> 16);
}
// async global->LDS DMA, 16 B/lane; LDS dest = wave-uniform base + lane*16
__device__ __forceinline__ void cp16(const unsigned short* g, unsigned short* l){
  __builtin_amdgcn_global_load_lds(
      (const __attribute__((address_space(1))) unsigned int*)g,
      (__attribute__((address_space(3))) unsigned int*)l, 16, 0, 0);
}

// ---------------- LayerNorm: f32 in -> bf16 out; one block per row of 1024 -----
__global__ __launch_bounds__(256) void ln_kernel(const float* __restrict__ x,
                                                 const float* __restrict__ g,
                                                 const float* __restrict__ bb,
                                                 unsigned short* __restrict__ y)
{
  int row = blockIdx.x, tid = threadIdx.x;
  float4 raw = ((const float4*)(x + (size_t)row * DIMM))[tid];
  float v0 = raw.x, v1 = raw.y, v2 = raw.z, v3 = raw.w;
  float s  = v0 + v1 + v2 + v3;
  float sq = v0*v0 + v1*v1 + v2*v2 + v3*v3;
  #pragma unroll
  for (int off = 32; off; off >>= 1){ s += __shfl_xor(s, off); sq += __shfl_xor(sq, off); }
  __shared__ float sm[8];
  int wave = tid >> 6, lane = tid & 63;
  if (lane == 0){ sm[wave] = s; sm[4 + wave] = sq; }
  __syncthreads();
  s  = sm[0] + sm[1] + sm[2] + sm[3];
  sq = sm[4] + sm[5] + sm[6] + sm[7];
  float mean = s * (1.f / DIMM);
  float var  = sq * (1.f / DIMM) - mean * mean;
  float rstd = rsqrtf(var + 1e-5f);
  float4 gr = ((const float4*)g)[tid];
  float4 br = ((const float4*)bb)[tid];
  ushort4 o;
  o.x = f2bf((v0 - mean) * rstd * gr.x + br.x);
  o.y = f2bf((v1 - mean) * rstd * gr.y + br.y);
  o.z = f2bf((v2 - mean) * rstd * gr.z + br.z);
  o.w = f2bf((v3 - mean) * rstd * gr.w + br.w);
  ((ushort4*)(y + (size_t)row * DIMM))[tid] = o;
}

// ---------------- Weight transpose: f32 [K,N] -> bf16 [N,K] --------------------
__global__ __launch_bounds__(256) void wt_kernel(const float* __restrict__ in,
                                                 unsigned short* __restrict__ out,
                                                 int K, int N)
{
  __shared__ float t[32][33];
  int tx = threadIdx.x & 31, ty = threadIdx.x >> 5;   // 32 x 8
  int k0 = blockIdx.y * 32, n0 = blockIdx.x * 32;
  #pragma unroll
  for (int i = 0; i < 4; i++)
    t[ty + i * 8][tx] = in[(size_t)(k0 + ty + i * 8) * N + n0 + tx];
  __syncthreads();
  #pragma unroll
  for (int i = 0; i < 4; i++)
    out[(size_t)(n0 + ty + i * 8) * K + k0 + tx] = f2bf(t[tx][ty + i * 8]);
}

// ---------------- ctx convert: f32 -> bf16, zero-padded to 384 rows ------------
#define CTXE (TCTX * BATCH * CTXD)   // 236544 valid elems
__global__ __launch_bounds__(256) void ctxcvt_kernel(const float* __restrict__ in,
                                                     unsigned short* __restrict__ out)
{
  int e = (blockIdx.x * 256 + threadIdx.x) * 4;    // up to 384*768
  float4 v;
  if (e < CTXE) v = *(const float4*)(in + e);
  else { v.x = 0.f; v.y = 0.f; v.z = 0.f; v.w = 0.f; }
  ushort4 o; o.x = f2bf(v.x); o.y = f2bf(v.y); o.z = f2bf(v.z); o.w = f2bf(v.w);
  *(ushort4*)(out + e) = o;
}

// ---------------- bf16 GEMM (B^T, BK=64, cp16 + XOR swizzle) -------------------
// C[M,N] = A[M,K] @ Bt[N,K]^T (+bias)(+res). 128x128 tile.
// LDS tiles unpadded [128][64] (128 B rows). Lane l of each cp16 fetches global
// col-group (l%8)^(l/8); frag reads XOR by row&7 -> bank-conflict-free (2-way).
template<int RESF, int CF32>
__global__ __launch_bounds__(256) void gemm_bt(
    const unsigned short* __restrict__ A, int lda,
    const unsigned short* __restrict__ Bt, int ldb,
    const float* __restrict__ bias, const void* __restrict__ resv,
    void* __restrict__ Cv, int ldc,
    int M, int N, int K)
{
  __shared__ __align__(16) unsigned short As[128][64];
  __shared__ __align__(16) unsigned short Bs[128][64];
  int tid = threadIdx.x;
  int n0 = blockIdx.x * 128, row0 = blockIdx.y * 128;
  int wave = tid >> 6, lane = tid & 63, quad = lane >> 4, l16 = lane & 15;
  int wm = (wave >> 1) * 64, wn = (wave & 1) * 64;
  int wrow = wave * 32;
  int lrow = lane >> 3, lgrp = lane & 7;
  int gcol = ((lgrp ^ lrow) * 8);

  f32x4 acc[4][4];
  #pragma unroll
  for (int mt = 0; mt < 4; mt++)
    #pragma unroll
    for (int nt = 0; nt < 4; nt++) acc[mt][nt] = 0.f;

  for (int k0 = 0; k0 < K; k0 += 64) {
    const unsigned short* ga = A  + (size_t)(row0 + wrow + lrow) * lda + k0 + gcol;
    const unsigned short* gb = Bt + (size_t)(n0  + wrow + lrow) * ldb + k0 + gcol;
    #pragma unroll
    for (int i = 0; i < 4; i++){
      cp16(ga + (size_t)(8 * i) * lda, &As[wrow + 8 * i][0]);
      cp16(gb + (size_t)(8 * i) * ldb, &Bs[wrow + 8 * i][0]);
    }
    __syncthreads();
    #pragma unroll
    for (int kc = 0; kc < 2; kc++){
      bf16x8 af[4], bf[4];
      #pragma unroll
      for (int mt = 0; mt < 4; mt++){
        int R = wm + mt * 16 + l16;
        af[mt] = *(const bf16x8*)&As[R][((kc * 4 + quad) ^ (R & 7)) * 8];
      }
      #pragma unroll
      for (int nt = 0; nt < 4; nt++){
        int R = wn + nt * 16 + l16;
        bf[nt] = *(const bf16x8*)&Bs[R][((kc * 4 + quad) ^ (R & 7)) * 8];
      }
      #pragma unroll
      for (int mt = 0; mt < 4; mt++)
        #pragma unroll
        for (int nt = 0; nt < 4; nt++)
          acc[mt][nt] = __builtin_amdgcn_mfma_f32_16x16x32_bf16(af[mt], bf[nt], acc[mt][nt], 0, 0, 0);
    }
    __syncthreads();
  }

  #pragma unroll
  for (int nt = 0; nt < 4; nt++){
    int c = n0 + wn + nt * 16 + l16;
    float bv = bias ? bias[c] : 0.f;
    #pragma unroll
    for (int mt = 0; mt < 4; mt++){
      int rbase = row0 + wm + mt * 16 + quad * 4;
      #pragma unroll
      for (int rr = 0; rr < 4; rr++){
        int r = rbase + rr;
        if (r < M) {
          float val = acc[mt][nt][rr] + bv;
          size_t idx = (size_t)r * ldc + c;
          if (RESF) val += ((const float*)resv)[idx];
          if (CF32) ((float*)Cv)[idx] = val;
          else      ((unsigned short*)Cv)[idx] = f2bf(val);
        }
      }
    }
  }
}

// ---------------- Fused FF1 + GEGLU (512 thr, 8 waves, 64x32 wave tile) --------
// Same 128x128 block tile + cp16/XOR-swizzle staging, but 8 waves arranged
// 2(M) x 4(N): accL[4][2]+accG[4][2] = 64 acc VGPRs/wave (was 128) ->
// __launch_bounds__(512,4) caps VGPR at 128 -> 4 waves/SIMD residency.
__global__ __launch_bounds__(512, 4) void ff1_geglu_bt(
    const unsigned short* __restrict__ A,     // [M,1024] bf16
    const unsigned short* __restrict__ BtW,   // [8192,1024] bf16 (transposed w_ff1)
    const float* __restrict__ bias,           // [8192] f32
    unsigned short* __restrict__ Z, int M)
{
  __shared__ __align__(16) unsigned short As[128][64];
  __shared__ __align__(16) unsigned short BsL[128][64];
  __shared__ __align__(16) unsigned short BsG[128][64];
  int tid = threadIdx.x;
  int n0 = blockIdx.x * 128, row0 = blockIdx.y * 128;
  int wave = tid >> 6, lane = tid & 63, quad = lane >> 4, l16 = lane & 15;
  int wm = (wave >> 2) * 64, wn = (wave & 3) * 32;
  int wrow = wave * 16;
  int lrow = lane >> 3, lgrp = lane & 7;
  int gcol = ((lgrp ^ lrow) * 8);

  f32x4 accL[4][2], accG[4][2];
  #pragma unroll
  for (int mt = 0; mt < 4; mt++)
    #pragma unroll
    for (int nt = 0; nt < 2; nt++){ accL[mt][nt] = 0.f; accG[mt][nt] = 0.f; }

  for (int k0 = 0; k0 < DIMM; k0 += 64) {
    const unsigned short* ga = A   + (size_t)(row0 + wrow + lrow) * DIMM + k0 + gcol;
    const unsigned short* gl = BtW + (size_t)(n0  + wrow + lrow) * DIMM + k0 + gcol;
    const unsigned short* gg = BtW + (size_t)(FFI + n0 + wrow + lrow) * DIMM + k0 + gcol;
    #pragma unroll
    for (int i = 0; i < 2; i++){
      cp16(ga + (size_t)(8 * i) * DIMM, &As[wrow + 8 * i][0]);
      cp16(gl + (size_t)(8 * i) * DIMM, &BsL[wrow + 8 * i][0]);
      cp16(gg + (size_t)(8 * i) * DIMM, &BsG[wrow + 8 * i][0]);
    }
    __syncthreads();
    #pragma unroll
    for (int kc = 0; kc < 2; kc++){
      bf16x8 af[4], bl[2], bg[2];
      #pragma unroll
      for (int mt = 0; mt < 4; mt++){
        int R = wm + mt * 16 + l16;
        af[mt] = *(const bf16x8*)&As[R][((kc * 4 + quad) ^ (R & 7)) * 8];
      }
      #pragma unroll
      for (int nt = 0; nt < 2; nt++){
        int R = wn + nt * 16 + l16;
        bl[nt] = *(const bf16x8*)&BsL[R][((kc * 4 + quad) ^ (R & 7)) * 8];
        bg[nt] = *(const bf16x8*)&BsG[R][((kc * 4 + quad) ^ (R & 7)) * 8];
      }
      #pragma unroll
      for (int mt = 0; mt < 4; mt++)
        #pragma unroll
        for (int nt = 0; nt < 2; nt++){
          accL[mt][nt] = __builtin_amdgcn_mfma_f32_16x16x32_bf16(af[mt], bl[nt], accL[mt][nt], 0, 0, 0);
          accG[mt][nt] = __builtin_amdgcn_mfma_f32_16x16x32_bf16(af[mt], bg[nt], accG[mt][nt], 0, 0, 0);
        }
    }
    __syncthreads();
  }

  #pragma unroll
  for (int nt = 0; nt < 2; nt++){
    int c = n0 + wn + nt * 16 + l16;
    float bvL = bias[c];
    float bvG = bias[c + FFI];
    #pragma unroll
    for (int mt = 0; mt < 4; mt++){
      int rbase = row0 + wm + mt * 16 + quad * 4;
      #pragma unroll
      for (int rr = 0; rr < 4; rr++){
        float lin = accL[mt][nt][rr] + bvL;
        float g   = accG[mt][nt][rr] + bvG;
        // gelu(g) = 0.5*g*(1+tanh(y)); tanh(y) = 1 - 2/(exp2(y*2*log2e)+1)
        float y = 0.7978845608028654f * (g + 0.044715f * g * g * g);
        float e = __builtin_amdgcn_exp2f(y * 2.8853900817779268f);
        float t = 1.f - 2.f * __builtin_amdgcn_rcpf(e + 1.f);
        Z[(size_t)(rbase + rr) * FFI + c] = f2bf(lin * 0.5f * g * (1.f + t));
      }
    }
  }
}

// ---------------- MFMA flash attention (swapped QK^T, in-register softmax) -----
// 512 threads = 8 waves, QBLK=256 (32 q-rows/wave, mt=2). Round-8 structure
// (verified 124 µs) + XCD-aware block remap: dispatch linear = y*8+x round-
// robins XCDs, so remapping bh = linear&63, qb = linear>>6 puts all 8 q-blocks
// of one (b,h) on XCD bh%8 -> that (b,h)'s 512 KB K/V stays in ONE L2
// (8 bh/XCD x 512 KB = 4 MB = L2 size). Bijective on the (8,64) grid.
__global__ __launch_bounds__(512, 4) void attn_mfma(
    const unsigned short* __restrict__ Q, int ldq,
    const unsigned short* __restrict__ Kb,
    const unsigned short* __restrict__ Vb, int ldkv,
    unsigned short* __restrict__ O,
    int S, int T, float scale)
{
  int tid = threadIdx.x, wave = tid >> 6, lane = tid & 63;
  int quad = lane >> 4, l16 = lane & 15;
  int linear = blockIdx.y * 8 + blockIdx.x;   // gridDim.x == 8
  int bh = linear & 63, qb = linear >> 6;
  int b = bh >> 4, h = bh & 15;
  int qw = qb * 256 + wave * 32;

  __shared__ __align__(16) unsigned short Ks[64][64];
  __shared__ __align__(16) unsigned short Vp[64][64];

  // Q fragments, pre-scaled by scale*log2(e): softmax runs in exp2 domain.
  float qs = scale * 1.44269504088896f;
  bf16x8 Qf[2][2];
  #pragma unroll
  for (int mt = 0; mt < 2; mt++)
    #pragma unroll
    for (int kc = 0; kc < 2; kc++){
      const unsigned short* qp = Q + ((size_t)b * S + qw + mt * 16 + l16) * ldq
                                   + h * DHEAD + kc * 32 + quad * 8;
      union { float4 v; unsigned short u[8]; } ld; ld.v = *(const float4*)qp;
      union { bf16x8 v; unsigned short u[8]; } sc;
      #pragma unroll
      for (int j = 0; j < 8; j++) sc.u[j] = f2bf(bf2f(ld.u[j]) * qs);
      Qf[mt][kc] = sc.v;
    }

  union { bf16x8 v; unsigned short u[8]; } ones;
  #pragma unroll
  for (int j = 0; j < 8; j++) ones.u[j] = 0x3F80;   // bf16 1.0

  f32x4 Oacc[2][4];
  f32x4 Lacc[2];
  #pragma unroll
  for (int mt = 0; mt < 2; mt++){
    Lacc[mt] = 0.f;
    #pragma unroll
    for (int nt = 0; nt < 4; nt++) Oacc[mt][nt] = 0.f;
  }

  int lrow = lane >> 3, lgrp = lane & 7;
  int gcol = (lgrp ^ lrow) * 8;
  // V permutation: thread owns key j=lane; logical col p(j) split chunk/elem
  int vj = lane;
  int vchunk = ((vj >> 5) << 2) | ((vj >> 2) & 3);   // = kc*4 + quad
  int velem  = (((vj >> 4) & 1) << 2) | (vj & 3);    // = h*4 + r
  int dbs = wave * 8;                                 // this wave's 8 d-rows

  for (int j0 = 0; j0 < T; j0 += 64){
    bool tail = (j0 + 64 > T);
    if (!tail){
      // full tile: async DMA, swizzle via pre-swizzled global source col
      const unsigned short* gk = Kb + ((size_t)b * T + j0 + wave * 8 + lrow) * ldkv
                                    + h * DHEAD + gcol;
      cp16(gk, &Ks[wave * 8][0]);
    } else {
      // masked tile (cross-attn): same swizzle, through VGPRs; 512 thr = 1 pass
      int key = tid >> 3, g = tid & 7;
      float4 kv;
      if (j0 + key < T) kv = *(const float4*)(Kb + ((size_t)b * T + j0 + key) * ldkv + h * DHEAD + g * 8);
      else { kv.x = 0.f; kv.y = 0.f; kv.z = 0.f; kv.w = 0.f; }
      *(float4*)&Ks[key][(g ^ (key & 7)) * 8] = kv;
    }
    {
      // V transpose+permute: thread reads V[j][dbs..dbs+7], scatters 8 shorts
      union { float4 v; unsigned short u[8]; } vv;
      if (j0 + vj < T) vv.v = *(const float4*)(Vb + ((size_t)b * T + j0 + vj) * ldkv + h * DHEAD + dbs);
      else { vv.v.x = 0.f; vv.v.y = 0.f; vv.v.z = 0.f; vv.v.w = 0.f; }
      #pragma unroll
      for (int u = 0; u < 8; u++)
        Vp[dbs + u][((vchunk ^ u) << 3) | velem] = vv.u[u];   // (dbs+u)&7 == u
    }
    __syncthreads();

    union pfu { bf16x8 v; __bf16 e[8]; } pf[2][2];   // [mt][kcHalf]
    #pragma unroll
    for (int mt = 0; mt < 2; mt++){
      f32x4 sT[4];
      __builtin_amdgcn_s_setprio(1);
      #pragma unroll
      for (int nt = 0; nt < 4; nt++){
        sT[nt] = 0.f;
        #pragma unroll
        for (int kc = 0; kc < 2; kc++){
          bf16x8 kf = *(const bf16x8*)&Ks[nt * 16 + l16][((kc * 4 + quad) ^ (l16 & 7)) * 8];
          sT[nt] = __builtin_amdgcn_mfma_f32_16x16x32_bf16(kf, Qf[mt][kc], sT[nt], 0, 0, 0);
        }
      }
      __builtin_amdgcn_s_setprio(0);
      #pragma unroll
      for (int nt = 0; nt < 4; nt++)
        #pragma unroll
        for (int rr = 0; rr < 4; rr++){
          float sv = sT[nt][rr];
          if (tail && (j0 + nt * 16 + quad * 4 + rr) >= T) sv = -1e30f;
          float p = __builtin_amdgcn_exp2f(fminf(sv, 108.f));
          pf[mt][nt >> 1].e[(nt & 1) * 4 + rr] = (__bf16)p;
        }
    }

    __builtin_amdgcn_s_setprio(1);
    #pragma unroll
    for (int kc = 0; kc < 2; kc++){
      #pragma unroll
      for (int nt = 0; nt < 4; nt++){
        int R = nt * 16 + l16;
        bf16x8 vf = *(const bf16x8*)&Vp[R][((kc * 4 + quad) ^ (R & 7)) * 8];
        #pragma unroll
        for (int mt = 0; mt < 2; mt++)
          Oacc[mt][nt] = __builtin_amdgcn_mfma_f32_16x16x32_bf16(pf[mt][kc].v, vf, Oacc[mt][nt], 0, 0, 0);
      }
      #pragma unroll
      for (int mt = 0; mt < 2; mt++)
        Lacc[mt] = __builtin_amdgcn_mfma_f32_16x16x32_bf16(pf[mt][kc].v, ones.v, Lacc[mt], 0, 0, 0);
    }
    __builtin_amdgcn_s_setprio(0);
    __syncthreads();
  }

  #pragma unroll
  for (int mt = 0; mt < 2; mt++){
    #pragma unroll
    for (int rr = 0; rr < 4; rr++){
      float inv = 1.f / Lacc[mt][rr];   // l for q-row = qw + mt*16 + quad*4 + rr
      #pragma unroll
      for (int nt = 0; nt < 4; nt++){
        size_t idx = ((size_t)b * S + qw + mt * 16 + quad * 4 + rr) * DIMM
                     + h * DHEAD + nt * 16 + l16;
        O[idx] = f2bf(Oacc[mt][nt][rr] * inv);
      }
    }
  }
}

extern "C" void kernel_launch(void* const* d_in, const int* in_sizes, int n_in,
                              void* d_out, int out_size, void* d_ws, size_t ws_size,
                              hipStream_t stream)
{
  const float* h0   = (const float*)d_in[0];
  const float* ctx  = (const float*)d_in[1];
  const float* wq1  = (const float*)d_in[2];
  const float* wk1  = (const float*)d_in[3];
  const float* wv1  = (const float*)d_in[4];
  const float* wo1  = (const float*)d_in[5];
  const float* bo1  = (const float*)d_in[6];
  const float* wq2  = (const float*)d_in[7];
  const float* wk2  = (const float*)d_in[8];
  const float* wv2  = (const float*)d_in[9];
  const float* wo2  = (const float*)d_in[10];
  const float* bo2  = (const float*)d_in[11];
  const float* wff1 = (const float*)d_in[12];
  const float* bff1 = (const float*)d_in[13];
  const float* wff2 = (const float*)d_in[14];
  const float* bff2 = (const float*)d_in[15];
  const float* ln1g = (const float*)d_in[16];
  const float* ln1b = (const float*)d_in[17];
  const float* ln2g = (const float*)d_in[18];
  const float* ln2b = (const float*)d_in[19];
  const float* ln3g = (const float*)d_in[20];
  const float* ln3b = (const float*)d_in[21];

  // ws (bf16 elems): xn(RD) | qkv(3RD) | arena(12M). 92 MB total.
  unsigned short* wsp = (unsigned short*)d_ws;
  const size_t RD = (size_t)BATCH * SEQ * DIMM;    // 8388608
  unsigned short* xn  = wsp;
  unsigned short* qkv = wsp + RD;                  // [8192,3072] fused; also q / zb
  unsigned short* ar  = wsp + 4 * RD;              // 12M-elem arena
  unsigned short* zb  = qkv;                       // FF half: [4096,4096] = 2RD
  float* hres = (float*)d_out;

  const size_t M1 = (size_t)1024 * 1024;
  const int ROWS = BATCH * SEQ;     // 8192
  const int CROWS = BATCH * TCTX;   // 308
  const float scale = 0.125f;
  dim3 blk(256);
  dim3 ablk(512);
  dim3 attn_grid(SEQ / 256, BATCH * NHEADS);

  // ---- stage 1: self-attention (fused QKV projection, N=3072) ----
  wt_kernel<<<dim3(32, 32), blk, 0, stream>>>(wq1, ar,          DIMM, DIMM);
  wt_kernel<<<dim3(32, 32), blk, 0, stream>>>(wk1, ar + M1,     DIMM, DIMM);
  wt_kernel<<<dim3(32, 32), blk, 0, stream>>>(wv1, ar + 2 * M1, DIMM, DIMM);
  wt_kernel<<<dim3(32, 32), blk, 0, stream>>>(wo1, ar + 3 * M1, DIMM, DIMM);
  ln_kernel<<<ROWS, blk, 0, stream>>>(h0, ln1g, ln1b, xn);
  gemm_bt<0,0><<<dim3(3072 / 128, ROWS / 128), blk, 0, stream>>>(
      xn, DIMM, ar, DIMM, nullptr, nullptr, qkv, 3072, ROWS, 3072, DIMM);
  attn_mfma<<<attn_grid, ablk, 0, stream>>>(qkv, 3072, qkv + 1024, qkv + 2048, 3072, xn, SEQ, SEQ, scale);
  gemm_bt<1,1><<<dim3(DIMM / 128, ROWS / 128), blk, 0, stream>>>(
      xn, DIMM, ar + 3 * M1, DIMM, bo1, h0, hres, DIMM, ROWS, DIMM, DIMM);

  // ---- stage 2: cross-attention (fused K/V, N=2048) ----
  unsigned short* wq2T  = ar;                       // [1024,1024]
  unsigned short* wkv2T = ar + M1;                  // [2048,768]
  unsigned short* wo2T  = ar + M1 + (size_t)2048 * CTXD;
  unsigned short* xc    = wo2T + M1;                // [384,768] padded bf16 ctx
  wt_kernel<<<dim3(32, 32), blk, 0, stream>>>(wq2, wq2T, DIMM, DIMM);
  wt_kernel<<<dim3(32, 24), blk, 0, stream>>>(wk2, wkv2T, CTXD, DIMM);
  wt_kernel<<<dim3(32, 24), blk, 0, stream>>>(wv2, wkv2T + (size_t)1024 * CTXD, CTXD, DIMM);
  wt_kernel<<<dim3(32, 32), blk, 0, stream>>>(wo2, wo2T, DIMM, DIMM);
  ctxcvt_kernel<<<(384 * CTXD / 4) / 256, blk, 0, stream>>>(ctx, xc);
  ln_kernel<<<ROWS, blk, 0, stream>>>(hres, ln2g, ln2b, xn);
  gemm_bt<0,0><<<dim3(DIMM / 128, ROWS / 128), blk, 0, stream>>>(
      xn, DIMM, wq2T, DIMM, nullptr, nullptr, qkv, DIMM, ROWS, DIMM, DIMM);
  unsigned short* kvc = qkv + RD;                   // [384,2048]
  gemm_bt<0,0><<<dim3(2048 / 128, 3), blk, 0, stream>>>(
      xc, CTXD, wkv2T, CTXD, nullptr, nullptr, kvc, 2048, CROWS, 2048, CTXD);
  attn_mfma<<<attn_grid, ablk, 0, stream>>>(qkv, 1024, kvc, kvc + 1024, 2048, xn, SEQ, TCTX, scale);
  gemm_bt<1,1><<<dim3(DIMM / 128, ROWS / 128), blk, 0, stream>>>(
      xn, DIMM, wo2T, DIMM, bo2, hres, hres, DIMM, ROWS, DIMM, DIMM);

  // ---- stage 3: GEGLU feed-forward (two M-halves; zb overlays qkv) ----
  unsigned short* wff1T = ar;              // [8192,1024]
  unsigned short* wff2T = ar + 8 * M1;     // [1024,4096]
  wt_kernel<<<dim3(256, 32),  blk, 0, stream>>>(wff1, wff1T, DIMM, 2 * FFI);
  wt_kernel<<<dim3(32, 128),  blk, 0, stream>>>(wff2, wff2T, FFI, DIMM);
  ln_kernel<<<ROWS, blk, 0, stream>>>(hres, ln3g, ln3b, xn);
  for (int half = 0; half < 2; half++){
    int r0 = half * 4096;
    ff1_geglu_bt<<<dim3(FFI / 128, 4096 / 128), dim3(512), 0, stream>>>(
        xn + (size_t)r0 * DIMM, wff1T, bff1, zb, 4096);
    gemm_bt<1,1><<<dim3(DIMM / 128, 4096 / 128), blk, 0, stream>>>(
        zb, FFI, wff2T, FFI, bff2, hres + (size_t)r0 * DIMM,
        hres + (size_t)r0 * DIMM, DIMM, 4096, DIMM, FFI);
  }
}

// Round 10
// 893.416 us; speedup vs baseline: 1.0346x; 1.0346x over previous
//
#include <hip/hip_runtime.h>

#define DIMM 1024
#define NHEADS 16
#define DHEAD 64
#define BATCH 4
#define SEQ 2048
#define TCTX 77
#define CTXD 768
#define FFI 4096

typedef float f32x4 __attribute__((ext_vector_type(4)));
typedef __bf16 bf16x8 __attribute__((ext_vector_type(8)));

__device__ __forceinline__ float bf2f(unsigned short u){
  union { unsigned int i; float f; } c; c.i = ((unsigned int)u) << 16; return c.f;
}
__device__ __forceinline__ unsigned short f2bf(float f){
  union { float f; unsigned int i; } c; c.f = f;
  unsigned int i = c.i;
  return (unsigned short)((i + 0x7fffu + ((i >> 16) & 1u)) >> 16);
}
// async global->LDS DMA, 16 B/lane; LDS dest = wave-uniform base + lane*16
__device__ __forceinline__ void cp16(const unsigned short* g, unsigned short* l){
  __builtin_amdgcn_global_load_lds(
      (const __attribute__((address_space(1))) unsigned int*)g,
      (__attribute__((address_space(3))) unsigned int*)l, 16, 0, 0);
}

// ---------------- LayerNorm: f32 in -> bf16 out; one block per row of 1024 -----
__global__ __launch_bounds__(256) void ln_kernel(const float* __restrict__ x,
                                                 const float* __restrict__ g,
                                                 const float* __restrict__ bb,
                                                 unsigned short* __restrict__ y)
{
  int row = blockIdx.x, tid = threadIdx.x;
  float4 raw = ((const float4*)(x + (size_t)row * DIMM))[tid];
  float v0 = raw.x, v1 = raw.y, v2 = raw.z, v3 = raw.w;
  float s  = v0 + v1 + v2 + v3;
  float sq = v0*v0 + v1*v1 + v2*v2 + v3*v3;
  #pragma unroll
  for (int off = 32; off; off >>= 1){ s += __shfl_xor(s, off); sq += __shfl_xor(sq, off); }
  __shared__ float sm[8];
  int wave = tid >> 6, lane = tid & 63;
  if (lane == 0){ sm[wave] = s; sm[4 + wave] = sq; }
  __syncthreads();
  s  = sm[0] + sm[1] + sm[2] + sm[3];
  sq = sm[4] + sm[5] + sm[6] + sm[7];
  float mean = s * (1.f / DIMM);
  float var  = sq * (1.f / DIMM) - mean * mean;
  float rstd = rsqrtf(var + 1e-5f);
  float4 gr = ((const float4*)g)[tid];
  float4 br = ((const float4*)bb)[tid];
  ushort4 o;
  o.x = f2bf((v0 - mean) * rstd * gr.x + br.x);
  o.y = f2bf((v1 - mean) * rstd * gr.y + br.y);
  o.z = f2bf((v2 - mean) * rstd * gr.z + br.z);
  o.w = f2bf((v3 - mean) * rstd * gr.w + br.w);
  ((ushort4*)(y + (size_t)row * DIMM))[tid] = o;
}

// ---------------- Weight transpose: f32 [K,N] -> bf16 [N,K] --------------------
__global__ __launch_bounds__(256) void wt_kernel(const float* __restrict__ in,
                                                 unsigned short* __restrict__ out,
                                                 int K, int N)
{
  __shared__ float t[32][33];
  int tx = threadIdx.x & 31, ty = threadIdx.x >> 5;   // 32 x 8
  int k0 = blockIdx.y * 32, n0 = blockIdx.x * 32;
  #pragma unroll
  for (int i = 0; i < 4; i++)
    t[ty + i * 8][tx] = in[(size_t)(k0 + ty + i * 8) * N + n0 + tx];
  __syncthreads();
  #pragma unroll
  for (int i = 0; i < 4; i++)
    out[(size_t)(n0 + ty + i * 8) * K + k0 + tx] = f2bf(t[tx][ty + i * 8]);
}

// ---------------- ctx convert: f32 -> bf16, zero-padded to 384 rows ------------
#define CTXE (TCTX * BATCH * CTXD)   // 236544 valid elems
__global__ __launch_bounds__(256) void ctxcvt_kernel(const float* __restrict__ in,
                                                     unsigned short* __restrict__ out)
{
  int e = (blockIdx.x * 256 + threadIdx.x) * 4;    // up to 384*768
  float4 v;
  if (e < CTXE) v = *(const float4*)(in + e);
  else { v.x = 0.f; v.y = 0.f; v.z = 0.f; v.w = 0.f; }
  ushort4 o; o.x = f2bf(v.x); o.y = f2bf(v.y); o.z = f2bf(v.z); o.w = f2bf(v.w);
  *(ushort4*)(out + e) = o;
}

// ---------------- bf16 GEMM (B^T, BK=64, cp16 + XOR swizzle) -------------------
// C[M,N] = A[M,K] @ Bt[N,K]^T (+bias)(+res). 128x128 tile.
// LDS tiles unpadded [128][64] (128 B rows). Lane l of each cp16 fetches global
// col-group (l%8)^(l/8); frag reads XOR by row&7 -> bank-conflict-free (2-way).
template<int RESF, int CF32>
__global__ __launch_bounds__(256) void gemm_bt(
    const unsigned short* __restrict__ A, int lda,
    const unsigned short* __restrict__ Bt, int ldb,
    const float* __restrict__ bias, const void* __restrict__ resv,
    void* __restrict__ Cv, int ldc,
    int M, int N, int K)
{
  __shared__ __align__(16) unsigned short As[128][64];
  __shared__ __align__(16) unsigned short Bs[128][64];
  int tid = threadIdx.x;
  int n0 = blockIdx.x * 128, row0 = blockIdx.y * 128;
  int wave = tid >> 6, lane = tid & 63, quad = lane >> 4, l16 = lane & 15;
  int wm = (wave >> 1) * 64, wn = (wave & 1) * 64;
  int wrow = wave * 32;
  int lrow = lane >> 3, lgrp = lane & 7;
  int gcol = ((lgrp ^ lrow) * 8);

  f32x4 acc[4][4];
  #pragma unroll
  for (int mt = 0; mt < 4; mt++)
    #pragma unroll
    for (int nt = 0; nt < 4; nt++) acc[mt][nt] = 0.f;

  for (int k0 = 0; k0 < K; k0 += 64) {
    const unsigned short* ga = A  + (size_t)(row0 + wrow + lrow) * lda + k0 + gcol;
    const unsigned short* gb = Bt + (size_t)(n0  + wrow + lrow) * ldb + k0 + gcol;
    #pragma unroll
    for (int i = 0; i < 4; i++){
      cp16(ga + (size_t)(8 * i) * lda, &As[wrow + 8 * i][0]);
      cp16(gb + (size_t)(8 * i) * ldb, &Bs[wrow + 8 * i][0]);
    }
    __syncthreads();
    #pragma unroll
    for (int kc = 0; kc < 2; kc++){
      bf16x8 af[4], bf[4];
      #pragma unroll
      for (int mt = 0; mt < 4; mt++){
        int R = wm + mt * 16 + l16;
        af[mt] = *(const bf16x8*)&As[R][((kc * 4 + quad) ^ (R & 7)) * 8];
      }
      #pragma unroll
      for (int nt = 0; nt < 4; nt++){
        int R = wn + nt * 16 + l16;
        bf[nt] = *(const bf16x8*)&Bs[R][((kc * 4 + quad) ^ (R & 7)) * 8];
      }
      #pragma unroll
      for (int mt = 0; mt < 4; mt++)
        #pragma unroll
        for (int nt = 0; nt < 4; nt++)
          acc[mt][nt] = __builtin_amdgcn_mfma_f32_16x16x32_bf16(af[mt], bf[nt], acc[mt][nt], 0, 0, 0);
    }
    __syncthreads();
  }

  #pragma unroll
  for (int nt = 0; nt < 4; nt++){
    int c = n0 + wn + nt * 16 + l16;
    float bv = bias ? bias[c] : 0.f;
    #pragma unroll
    for (int mt = 0; mt < 4; mt++){
      int rbase = row0 + wm + mt * 16 + quad * 4;
      #pragma unroll
      for (int rr = 0; rr < 4; rr++){
        int r = rbase + rr;
        if (r < M) {
          float val = acc[mt][nt][rr] + bv;
          size_t idx = (size_t)r * ldc + c;
          if (RESF) val += ((const float*)resv)[idx];
          if (CF32) ((float*)Cv)[idx] = val;
          else      ((unsigned short*)Cv)[idx] = f2bf(val);
        }
      }
    }
  }
}

// ---------------- Fused FF1 + GEGLU (512 thr, 8 waves, 64x32 wave tile) --------
// Same 128x128 block tile + cp16/XOR-swizzle staging, but 8 waves arranged
// 2(M) x 4(N): accL[4][2]+accG[4][2] = 64 acc VGPRs/wave (was 128) ->
// __launch_bounds__(512,4) caps VGPR at 128 -> 4 waves/SIMD residency.
__global__ __launch_bounds__(512, 4) void ff1_geglu_bt(
    const unsigned short* __restrict__ A,     // [M,1024] bf16
    const unsigned short* __restrict__ BtW,   // [8192,1024] bf16 (transposed w_ff1)
    const float* __restrict__ bias,           // [8192] f32
    unsigned short* __restrict__ Z, int M)
{
  __shared__ __align__(16) unsigned short As[128][64];
  __shared__ __align__(16) unsigned short BsL[128][64];
  __shared__ __align__(16) unsigned short BsG[128][64];
  int tid = threadIdx.x;
  int n0 = blockIdx.x * 128, row0 = blockIdx.y * 128;
  int wave = tid >> 6, lane = tid & 63, quad = lane >> 4, l16 = lane & 15;
  int wm = (wave >> 2) * 64, wn = (wave & 3) * 32;
  int wrow = wave * 16;
  int lrow = lane >> 3, lgrp = lane & 7;
  int gcol = ((lgrp ^ lrow) * 8);

  f32x4 accL[4][2], accG[4][2];
  #pragma unroll
  for (int mt = 0; mt < 4; mt++)
    #pragma unroll
    for (int nt = 0; nt < 2; nt++){ accL[mt][nt] = 0.f; accG[mt][nt] = 0.f; }

  for (int k0 = 0; k0 < DIMM; k0 += 64) {
    const unsigned short* ga = A   + (size_t)(row0 + wrow + lrow) * DIMM + k0 + gcol;
    const unsigned short* gl = BtW + (size_t)(n0  + wrow + lrow) * DIMM + k0 + gcol;
    const unsigned short* gg = BtW + (size_t)(FFI + n0 + wrow + lrow) * DIMM + k0 + gcol;
    #pragma unroll
    for (int i = 0; i < 2; i++){
      cp16(ga + (size_t)(8 * i) * DIMM, &As[wrow + 8 * i][0]);
      cp16(gl + (size_t)(8 * i) * DIMM, &BsL[wrow + 8 * i][0]);
      cp16(gg + (size_t)(8 * i) * DIMM, &BsG[wrow + 8 * i][0]);
    }
    __syncthreads();
    #pragma unroll
    for (int kc = 0; kc < 2; kc++){
      bf16x8 af[4], bl[2], bg[2];
      #pragma unroll
      for (int mt = 0; mt < 4; mt++){
        int R = wm + mt * 16 + l16;
        af[mt] = *(const bf16x8*)&As[R][((kc * 4 + quad) ^ (R & 7)) * 8];
      }
      #pragma unroll
      for (int nt = 0; nt < 2; nt++){
        int R = wn + nt * 16 + l16;
        bl[nt] = *(const bf16x8*)&BsL[R][((kc * 4 + quad) ^ (R & 7)) * 8];
        bg[nt] = *(const bf16x8*)&BsG[R][((kc * 4 + quad) ^ (R & 7)) * 8];
      }
      #pragma unroll
      for (int mt = 0; mt < 4; mt++)
        #pragma unroll
        for (int nt = 0; nt < 2; nt++){
          accL[mt][nt] = __builtin_amdgcn_mfma_f32_16x16x32_bf16(af[mt], bl[nt], accL[mt][nt], 0, 0, 0);
          accG[mt][nt] = __builtin_amdgcn_mfma_f32_16x16x32_bf16(af[mt], bg[nt], accG[mt][nt], 0, 0, 0);
        }
    }
    __syncthreads();
  }

  #pragma unroll
  for (int nt = 0; nt < 2; nt++){
    int c = n0 + wn + nt * 16 + l16;
    float bvL = bias[c];
    float bvG = bias[c + FFI];
    #pragma unroll
    for (int mt = 0; mt < 4; mt++){
      int rbase = row0 + wm + mt * 16 + quad * 4;
      #pragma unroll
      for (int rr = 0; rr < 4; rr++){
        float lin = accL[mt][nt][rr] + bvL;
        float g   = accG[mt][nt][rr] + bvG;
        // gelu(g) = 0.5*g*(1+tanh(y)); tanh(y) = 1 - 2/(exp2(y*2*log2e)+1)
        float y = 0.7978845608028654f * (g + 0.044715f * g * g * g);
        float e = __builtin_amdgcn_exp2f(y * 2.8853900817779268f);
        float t = 1.f - 2.f * __builtin_amdgcn_rcpf(e + 1.f);
        Z[(size_t)(rbase + rr) * FFI + c] = f2bf(lin * 0.5f * g * (1.f + t));
      }
    }
  }
}

// ---------------- MFMA flash attention (KVBLK=128, templated tail) -------------
// 512 threads = 8 waves, QBLK=256 (32 q-rows/wave, mt=2). Round-9 structure
// (XCD remap, ones-MFMA denom, setprio) with:
//  - KVBLK=128: Ks[128][64] + Vp[64][128] (32 KB), 2 sub-tiles per barrier
//    period -> barriers/loop/setprio overhead halves. Bank residues identical
//    to the verified 64-key layout (row strides 128/256 B are both ==0 mod
//    32 banks), so conflict-free staging/reads carry over.
//  - template<int FULL>: FULL=1 (self-attn, T%128==0) compiles out all tail
//    masks and guards; FULL=0 keeps the masked VGPR staging path.
template<int FULL>
__global__ __launch_bounds__(512, 4) void attn_mfma(
    const unsigned short* __restrict__ Q, int ldq,
    const unsigned short* __restrict__ Kb,
    const unsigned short* __restrict__ Vb, int ldkv,
    unsigned short* __restrict__ O,
    int S, int T, float scale)
{
  int tid = threadIdx.x, wave = tid >> 6, lane = tid & 63;
  int quad = lane >> 4, l16 = lane & 15;
  int linear = blockIdx.y * 8 + blockIdx.x;   // gridDim.x == 8
  int bh = linear & 63, qb = linear >> 6;
  int b = bh >> 4, h = bh & 15;
  int qw = qb * 256 + wave * 32;

  __shared__ __align__(16) unsigned short Ks[128][64];
  __shared__ __align__(16) unsigned short Vp[64][128];

  // Q fragments, pre-scaled by scale*log2(e): softmax runs in exp2 domain.
  float qs = scale * 1.44269504088896f;
  bf16x8 Qf[2][2];
  #pragma unroll
  for (int mt = 0; mt < 2; mt++)
    #pragma unroll
    for (int kc = 0; kc < 2; kc++){
      const unsigned short* qp = Q + ((size_t)b * S + qw + mt * 16 + l16) * ldq
                                   + h * DHEAD + kc * 32 + quad * 8;
      union { float4 v; unsigned short u[8]; } ld; ld.v = *(const float4*)qp;
      union { bf16x8 v; unsigned short u[8]; } sc;
      #pragma unroll
      for (int j = 0; j < 8; j++) sc.u[j] = f2bf(bf2f(ld.u[j]) * qs);
      Qf[mt][kc] = sc.v;
    }

  union { bf16x8 v; unsigned short u[8]; } ones;
  #pragma unroll
  for (int j = 0; j < 8; j++) ones.u[j] = 0x3F80;   // bf16 1.0

  f32x4 Oacc[2][4];
  f32x4 Lacc[2];
  #pragma unroll
  for (int mt = 0; mt < 2; mt++){
    Lacc[mt] = 0.f;
    #pragma unroll
    for (int nt = 0; nt < 4; nt++) Oacc[mt][nt] = 0.f;
  }

  int lrow = lane >> 3, lgrp = lane & 7;
  int gcol = (lgrp ^ lrow) * 8;
  // V permutation: thread owns key j=lane; logical col p(j) split chunk/elem
  int vj = lane;
  int vchunk = ((vj >> 5) << 2) | ((vj >> 2) & 3);   // = kc*4 + quad
  int velem  = (((vj >> 4) & 1) << 2) | (vj & 3);    // = h*4 + r
  int dbs = wave * 8;                                 // this wave's 8 d-rows

  for (int j0 = 0; j0 < T; j0 += 128){
    if (FULL){
      // K: rows wave*16..wave*16+15 via 2 cp16 (swizzled global source col)
      const unsigned short* gk = Kb + ((size_t)b * T + j0 + wave * 16 + lrow) * ldkv
                                    + h * DHEAD + gcol;
      cp16(gk,                    &Ks[wave * 16][0]);
      cp16(gk + (size_t)8 * ldkv, &Ks[wave * 16 + 8][0]);
    } else {
      // masked K (cross-attn): 2 passes x 64 keys, through VGPRs
      #pragma unroll
      for (int p = 0; p < 2; p++){
        int key = p * 64 + (tid >> 3), g = tid & 7;
        float4 kv;
        if (j0 + key < T) kv = *(const float4*)(Kb + ((size_t)b * T + j0 + key) * ldkv + h * DHEAD + g * 8);
        else { kv.x = 0.f; kv.y = 0.f; kv.z = 0.f; kv.w = 0.f; }
        *(float4*)&Ks[key][(g ^ (key & 7)) * 8] = kv;
      }
    }
    // V transpose+permute: thread reads V[s*64+vj][dbs..dbs+7], scatters 8
    #pragma unroll
    for (int s = 0; s < 2; s++){
      union { float4 v; unsigned short u[8]; } vv;
      bool ok = FULL ? true : (j0 + s * 64 + vj < T);
      if (ok) vv.v = *(const float4*)(Vb + ((size_t)b * T + j0 + s * 64 + vj) * ldkv + h * DHEAD + dbs);
      else { vv.v.x = 0.f; vv.v.y = 0.f; vv.v.z = 0.f; vv.v.w = 0.f; }
      #pragma unroll
      for (int u = 0; u < 8; u++)
        Vp[dbs + u][s * 64 + (((vchunk ^ u) << 3) | velem)] = vv.u[u];   // (dbs+u)&7 == u
    }
    __syncthreads();

    #pragma unroll
    for (int s = 0; s < 2; s++){
      union pfu { bf16x8 v; __bf16 e[8]; } pf[2][2];   // [mt][kcHalf]
      #pragma unroll
      for (int mt = 0; mt < 2; mt++){
        f32x4 sT[4];
        __builtin_amdgcn_s_setprio(1);
        #pragma unroll
        for (int nt = 0; nt < 4; nt++){
          sT[nt] = 0.f;
          #pragma unroll
          for (int kc = 0; kc < 2; kc++){
            bf16x8 kf = *(const bf16x8*)&Ks[s * 64 + nt * 16 + l16][((kc * 4 + quad) ^ (l16 & 7)) * 8];
            sT[nt] = __builtin_amdgcn_mfma_f32_16x16x32_bf16(kf, Qf[mt][kc], sT[nt], 0, 0, 0);
          }
        }
        __builtin_amdgcn_s_setprio(0);
        #pragma unroll
        for (int nt = 0; nt < 4; nt++)
          #pragma unroll
          for (int rr = 0; rr < 4; rr++){
            float sv = sT[nt][rr];
            if (!FULL && (j0 + s * 64 + nt * 16 + quad * 4 + rr) >= T) sv = -1e30f;
            float p = __builtin_amdgcn_exp2f(fminf(sv, 108.f));
            pf[mt][nt >> 1].e[(nt & 1) * 4 + rr] = (__bf16)p;
          }
      }

      __builtin_amdgcn_s_setprio(1);
      #pragma unroll
      for (int kc = 0; kc < 2; kc++){
        #pragma unroll
        for (int nt = 0; nt < 4; nt++){
          int R = nt * 16 + l16;
          bf16x8 vf = *(const bf16x8*)&Vp[R][s * 64 + ((kc * 4 + quad) ^ (R & 7)) * 8];
          #pragma unroll
          for (int mt = 0; mt < 2; mt++)
            Oacc[mt][nt] = __builtin_amdgcn_mfma_f32_16x16x32_bf16(pf[mt][kc].v, vf, Oacc[mt][nt], 0, 0, 0);
        }
        #pragma unroll
        for (int mt = 0; mt < 2; mt++)
          Lacc[mt] = __builtin_amdgcn_mfma_f32_16x16x32_bf16(pf[mt][kc].v, ones.v, Lacc[mt], 0, 0, 0);
      }
      __builtin_amdgcn_s_setprio(0);
    }
    __syncthreads();
  }

  #pragma unroll
  for (int mt = 0; mt < 2; mt++){
    #pragma unroll
    for (int rr = 0; rr < 4; rr++){
      float inv = 1.f / Lacc[mt][rr];   // l for q-row = qw + mt*16 + quad*4 + rr
      #pragma unroll
      for (int nt = 0; nt < 4; nt++){
        size_t idx = ((size_t)b * S + qw + mt * 16 + quad * 4 + rr) * DIMM
                     + h * DHEAD + nt * 16 + l16;
        O[idx] = f2bf(Oacc[mt][nt][rr] * inv);
      }
    }
  }
}

extern "C" void kernel_launch(void* const* d_in, const int* in_sizes, int n_in,
                              void* d_out, int out_size, void* d_ws, size_t ws_size,
                              hipStream_t stream)
{
  const float* h0   = (const float*)d_in[0];
  const float* ctx  = (const float*)d_in[1];
  const float* wq1  = (const float*)d_in[2];
  const float* wk1  = (const float*)d_in[3];
  const float* wv1  = (const float*)d_in[4];
  const float* wo1  = (const float*)d_in[5];
  const float* bo1  = (const float*)d_in[6];
  const float* wq2  = (const float*)d_in[7];
  const float* wk2  = (const float*)d_in[8];
  const float* wv2  = (const float*)d_in[9];
  const float* wo2  = (const float*)d_in[10];
  const float* bo2  = (const float*)d_in[11];
  const float* wff1 = (const float*)d_in[12];
  const float* bff1 = (const float*)d_in[13];
  const float* wff2 = (const float*)d_in[14];
  const float* bff2 = (const float*)d_in[15];
  const float* ln1g = (const float*)d_in[16];
  const float* ln1b = (const float*)d_in[17];
  const float* ln2g = (const float*)d_in[18];
  const float* ln2b = (const float*)d_in[19];
  const float* ln3g = (const float*)d_in[20];
  const float* ln3b = (const float*)d_in[21];

  // ws (bf16 elems): xn(RD) | qkv(3RD) | arena(12M). 92 MB total.
  unsigned short* wsp = (unsigned short*)d_ws;
  const size_t RD = (size_t)BATCH * SEQ * DIMM;    // 8388608
  unsigned short* xn  = wsp;
  unsigned short* qkv = wsp + RD;                  // [8192,3072] fused; also q / zb
  unsigned short* ar  = wsp + 4 * RD;              // 12M-elem arena
  unsigned short* zb  = qkv;                       // FF half: [4096,4096] = 2RD
  float* hres = (float*)d_out;

  const size_t M1 = (size_t)1024 * 1024;
  const int ROWS = BATCH * SEQ;     // 8192
  const int CROWS = BATCH * TCTX;   // 308
  const float scale = 0.125f;
  dim3 blk(256);
  dim3 ablk(512);
  dim3 attn_grid(SEQ / 256, BATCH * NHEADS);

  // ---- stage 1: self-attention (fused QKV projection, N=3072) ----
  wt_kernel<<<dim3(32, 32), blk, 0, stream>>>(wq1, ar,          DIMM, DIMM);
  wt_kernel<<<dim3(32, 32), blk, 0, stream>>>(wk1, ar + M1,     DIMM, DIMM);
  wt_kernel<<<dim3(32, 32), blk, 0, stream>>>(wv1, ar + 2 * M1, DIMM, DIMM);
  wt_kernel<<<dim3(32, 32), blk, 0, stream>>>(wo1, ar + 3 * M1, DIMM, DIMM);
  ln_kernel<<<ROWS, blk, 0, stream>>>(h0, ln1g, ln1b, xn);
  gemm_bt<0,0><<<dim3(3072 / 128, ROWS / 128), blk, 0, stream>>>(
      xn, DIMM, ar, DIMM, nullptr, nullptr, qkv, 3072, ROWS, 3072, DIMM);
  attn_mfma<1><<<attn_grid, ablk, 0, stream>>>(qkv, 3072, qkv + 1024, qkv + 2048, 3072, xn, SEQ, SEQ, scale);
  gemm_bt<1,1><<<dim3(DIMM / 128, ROWS / 128), blk, 0, stream>>>(
      xn, DIMM, ar + 3 * M1, DIMM, bo1, h0, hres, DIMM, ROWS, DIMM, DIMM);

  // ---- stage 2: cross-attention (fused K/V, N=2048) ----
  unsigned short* wq2T  = ar;                       // [1024,1024]
  unsigned short* wkv2T = ar + M1;                  // [2048,768]
  unsigned short* wo2T  = ar + M1 + (size_t)2048 * CTXD;
  unsigned short* xc    = wo2T + M1;                // [384,768] padded bf16 ctx
  wt_kernel<<<dim3(32, 32), blk, 0, stream>>>(wq2, wq2T, DIMM, DIMM);
  wt_kernel<<<dim3(32, 24), blk, 0, stream>>>(wk2, wkv2T, CTXD, DIMM);
  wt_kernel<<<dim3(32, 24), blk, 0, stream>>>(wv2, wkv2T + (size_t)1024 * CTXD, CTXD, DIMM);
  wt_kernel<<<dim3(32, 32), blk, 0, stream>>>(wo2, wo2T, DIMM, DIMM);
  ctxcvt_kernel<<<(384 * CTXD / 4) / 256, blk, 0, stream>>>(ctx, xc);
  ln_kernel<<<ROWS, blk, 0, stream>>>(hres, ln2g, ln2b, xn);
  gemm_bt<0,0><<<dim3(DIMM / 128, ROWS / 128), blk, 0, stream>>>(
      xn, DIMM, wq2T, DIMM, nullptr, nullptr, qkv, DIMM, ROWS, DIMM, DIMM);
  unsigned short* kvc = qkv + RD;                   // [384,2048]
  gemm_bt<0,0><<<dim3(2048 / 128, 3), blk, 0, stream>>>(
      xc, CTXD, wkv2T, CTXD, nullptr, nullptr, kvc, 2048, CROWS, 2048, CTXD);
  attn_mfma<0><<<attn_grid, ablk, 0, stream>>>(qkv, 1024, kvc, kvc + 1024, 2048, xn, SEQ, TCTX, scale);
  gemm_bt<1,1><<<dim3(DIMM / 128, ROWS / 128), blk, 0, stream>>>(
      xn, DIMM, wo2T, DIMM, bo2, hres, hres, DIMM, ROWS, DIMM, DIMM);

  // ---- stage 3: GEGLU feed-forward (two M-halves; zb overlays qkv) ----
  unsigned short* wff1T = ar;              // [8192,1024]
  unsigned short* wff2T = ar + 8 * M1;     // [1024,4096]
  wt_kernel<<<dim3(256, 32),  blk, 0, stream>>>(wff1, wff1T, DIMM, 2 * FFI);
  wt_kernel<<<dim3(32, 128),  blk, 0, stream>>>(wff2, wff2T, FFI, DIMM);
  ln_kernel<<<ROWS, blk, 0, stream>>>(hres, ln3g, ln3b, xn);
  for (int half = 0; half < 2; half++){
    int r0 = half * 4096;
    ff1_geglu_bt<<<dim3(FFI / 128, 4096 / 128), dim3(512), 0, stream>>>(
        xn + (size_t)r0 * DIMM, wff1T, bff1, zb, 4096);
    gemm_bt<1,1><<<dim3(DIMM / 128, 4096 / 128), blk, 0, stream>>>(
        zb, FFI, wff2T, FFI, bff2, hres + (size_t)r0 * DIMM,
        hres + (size_t)r0 * DIMM, DIMM, 4096, DIMM, FFI);
  }
}